// Round 9
// baseline (8502.984 us; speedup 1.0000x reference)
//
#include <hip/hip_runtime.h>
#include <hip/hip_cooperative_groups.h>
#include <math.h>

namespace cg = cooperative_groups;

#define B_  2048
#define S_  32
#define T_  32
#define D_  128
#define H_  256
#define G3  768
#define VT_ 256
#define BOW_ 1

typedef __attribute__((ext_vector_type(8))) short short8;
typedef __attribute__((ext_vector_type(4))) float f32x4;
typedef __attribute__((ext_vector_type(8))) unsigned short us8;
typedef unsigned short u16;

__device__ inline u16 f2bf(float x) {
  union { float f; unsigned u; } v; v.f = x;
  unsigned r = v.u + 0x7FFFu + ((v.u >> 16) & 1u);
  return (u16)(r >> 16);
}
__device__ inline float bf2f(u16 b) {
  union { unsigned u; float f; } v; v.u = ((unsigned)b) << 16; return v.f;
}
__device__ inline int swz(int r) { return ((r ^ (r >> 3)) & 7) << 3; }
__device__ inline float sigm(float x) { return 1.f / (1.f + expf(-x)); }

// ---------------- weight transpose + split ----------------
struct TMat { const float* src; u16* dhi; u16* dlo; int R; int C; int tile0; };
struct TPack { TMat m[10]; };

__global__ __launch_bounds__(256)
void wsplit_t(TPack P) {
  int bx = blockIdx.x;
  TMat M = P.m[0];
  #pragma unroll
  for (int i = 1; i < 10; i++) if (bx >= P.m[i].tile0) M = P.m[i];
  int ti = bx - M.tile0;
  int tilesR = M.R >> 6;
  int rt = ti % tilesR, ct = ti / tilesR;
  int r0 = rt * 64, c0 = ct * 64;
  __shared__ float ts[64][65];
  int tid = threadIdx.x;
  int cx = tid & 63, ry = tid >> 6;
  #pragma unroll
  for (int i = 0; i < 16; i++) {
    int r = ry * 16 + i;
    ts[r][cx] = M.src[(size_t)(r0 + r) * M.C + c0 + cx];
  }
  __syncthreads();
  int rx = tid & 63, cy = tid >> 6;
  #pragma unroll
  for (int i = 0; i < 16; i++) {
    int cc = cy * 16 + i;
    float v = ts[rx][cc];
    u16 hi = f2bf(v);
    size_t o = (size_t)(c0 + cc) * M.R + r0 + rx;
    M.dhi[o] = hi;
    M.dlo[o] = f2bf(v - bf2f(hi));
  }
}

__global__ __launch_bounds__(256)
void esplit(const float* a, const float* b, u16* ah, u16* al, u16* bh, u16* bl, int n) {
  int i = blockIdx.x * 256 + threadIdx.x;
  if (i >= 2 * n) return;
  const float* s = (i < n) ? a : b;
  u16* dh = (i < n) ? ah : bh;
  u16* dl = (i < n) ? al : bl;
  int j = (i < n) ? i : i - n;
  float v = s[j];
  u16 hi = f2bf(v);
  dh[j] = hi; dl[j] = f2bf(v - bf2f(hi));
}

// ---------------- plane GEMM (tables / proj / p0 / logits) ----------------
struct PLeg {
  const u16* Ahi; const u16* Alo; int lda;
  const u16* Bthi; const u16* Btlo; int ldb;
  const float* bias; void* C; int ldc; int cmode;  // 0=f32, 1=bf16, 2=logits-layout
  int M, N, K;
};

__global__ __launch_bounds__(256)
void gemm_pl(PLeg l0, PLeg l1) {
  PLeg L = blockIdx.z ? l1 : l0;
  int n0 = blockIdx.x * 128; if (n0 >= L.N) return;
  int m0 = blockIdx.y * 128; if (m0 >= L.M) return;
  __shared__ u16 As[128 * 64];
  __shared__ u16 Bs[128 * 64];
  int tid = threadIdx.x;
  int lane = tid & 63, wv = tid >> 6;
  int wr = (wv >> 1) * 64, wc = (wv & 1) * 64;
  int fr = lane & 15, fk = (lane >> 4) * 8;
  f32x4 acc[4][4];
  #pragma unroll
  for (int m = 0; m < 4; m++)
    #pragma unroll
    for (int n = 0; n < 4; n++) acc[m][n] = (f32x4){0.f, 0.f, 0.f, 0.f};

  int s_row = tid >> 1, s_part = tid & 1;

  for (int k0 = 0; k0 < L.K; k0 += 32) {
    if (k0) __syncthreads();
    int swA = swz(s_row);
    {
      const u16* src = (s_part ? L.Alo : L.Ahi) + (size_t)(m0 + s_row) * L.lda + k0;
      #pragma unroll
      for (int q = 0; q < 4; q++)
        *(us8*)&As[(s_row * 64 + s_part * 32 + q * 8) ^ swA] = *(const us8*)(src + q * 8);
    }
    {
      const u16* src = (s_part ? L.Btlo : L.Bthi) + (size_t)(n0 + s_row) * L.ldb + k0;
      #pragma unroll
      for (int q = 0; q < 4; q++)
        *(us8*)&Bs[(s_row * 64 + s_part * 32 + q * 8) ^ swA] = *(const us8*)(src + q * 8);
    }
    __syncthreads();
    short8 bhi[4], blo[4];
    #pragma unroll
    for (int n = 0; n < 4; n++) {
      int cc = wc + n * 16 + fr; int sw = swz(cc);
      bhi[n] = *(const short8*)&Bs[(cc * 64 + fk) ^ sw];
      blo[n] = *(const short8*)&Bs[(cc * 64 + 32 + fk) ^ sw];
    }
    #pragma unroll
    for (int m = 0; m < 4; m++) {
      int r = wr + m * 16 + fr; int sw = swz(r);
      short8 ahi = *(const short8*)&As[(r * 64 + fk) ^ sw];
      short8 alo = *(const short8*)&As[(r * 64 + 32 + fk) ^ sw];
      #pragma unroll
      for (int n = 0; n < 4; n++) {
        acc[m][n] = __builtin_amdgcn_mfma_f32_16x16x32_bf16(ahi, bhi[n], acc[m][n], 0, 0, 0);
        acc[m][n] = __builtin_amdgcn_mfma_f32_16x16x32_bf16(ahi, blo[n], acc[m][n], 0, 0, 0);
        acc[m][n] = __builtin_amdgcn_mfma_f32_16x16x32_bf16(alo, bhi[n], acc[m][n], 0, 0, 0);
      }
    }
  }
  int rbase = (lane >> 4) * 4;
  #pragma unroll
  for (int m = 0; m < 4; m++)
    #pragma unroll
    for (int rr = 0; rr < 4; rr++) {
      int row = m0 + wr + m * 16 + rbase + rr;
      #pragma unroll
      for (int n = 0; n < 4; n++) {
        int col = n0 + wc + n * 16 + fr;
        float v = acc[m][n][rr];
        if (L.bias) v += L.bias[col];
        if (L.cmode == 0)      ((float*)L.C)[(size_t)row * L.ldc + col] = v;
        else if (L.cmode == 1) ((u16*)L.C)[(size_t)row * L.ldc + col] = f2bf(v);
        else {
          size_t o = (((size_t)(row & (B_ - 1))) * T_ + (row >> 11)) * VT_ + col;
          ((float*)L.C)[o] = v;
        }
      }
    }
}

// ---------------- initial attention (regular launch) ----------------
__global__ __launch_bounds__(256)
void attend_k(const u16* __restrict__ projbf, const u16* __restrict__ ssH,
              const float* __restrict__ p, const float* __restrict__ att_v,
              u16* __restrict__ ctxh, u16* __restrict__ ctxl) {
  int b = blockIdx.x;
  int tid = threadIdx.x;
  int lane = tid & 63;
  int wv = tid >> 6;
  __shared__ float e_s[S_];
  __shared__ float w_s[S_];
  float pq[4], vq[4];
  #pragma unroll
  for (int q = 0; q < 4; q++) {
    pq[q] = p[(size_t)b * H_ + q * 64 + lane];
    vq[q] = att_v[q * 64 + lane];
  }
  float pv[8][4];
  #pragma unroll
  for (int i = 0; i < 8; i++) {
    const u16* pr = projbf + ((size_t)(wv * 8 + i) * B_ + b) * H_;
    #pragma unroll
    for (int q = 0; q < 4; q++) pv[i][q] = bf2f(pr[q * 64 + lane]);
  }
  u16 sv[S_];
  #pragma unroll
  for (int s = 0; s < S_; s++) sv[s] = ssH[((size_t)s * B_ + b) * H_ + tid];

  #pragma unroll
  for (int i = 0; i < 8; i++) {
    float part = 0.f;
    #pragma unroll
    for (int q = 0; q < 4; q++)
      part += tanhf(pv[i][q] + pq[q]) * vq[q];
    #pragma unroll
    for (int off = 32; off; off >>= 1)
      part += __shfl_xor(part, off);
    if (lane == 0) e_s[wv * 8 + i] = part;
  }
  __syncthreads();
  float m = -1e30f;
  #pragma unroll
  for (int s = 0; s < S_; s++) m = fmaxf(m, e_s[s]);
  float den = 0.f;
  #pragma unroll
  for (int s = 0; s < S_; s++) den += expf(e_s[s] - m);
  if (tid < S_) w_s[tid] = expf(e_s[tid] - m) / den;
  __syncthreads();
  float acc = 0.f;
  #pragma unroll
  for (int s = 0; s < S_; s++)
    acc = fmaf(w_s[s], bf2f(sv[s]), acc);
  u16 hi = f2bf(acc);
  size_t o = (size_t)b * H_ + tid;
  ctxh[o] = hi; ctxl[o] = f2bf(acc - bf2f(hi));
}

// ================= fused encoder (coop or per-step) =================
struct EncP {
  u16* hH[2][2]; u16* hL[2][2];     // [parity][dir]
  float* hF[2][2];
  const u16 *bUH[2], *bUL[2];
  const float *gxT[2];
  const float *bias[2];
  u16 *ssH, *ssL;
  const int *ids;
};

__device__ __forceinline__ void enc_step_body(const EncP& P, int s, u16* As) {
  int bid = blockIdx.x;
  int d = bid >> 8, rem = bid & 255;
  int x = rem & 3, y = rem >> 2;
  int m0 = y * 32;
  int tid = threadIdx.x;
  int lane = tid & 63, wv = tid >> 6;
  int fr = lane & 15, kq = lane >> 4;
  int jn = x * 64 + wv * 16 + fr;
  const size_t BHsz = (size_t)B_ * H_;

  const u16 *bUH = P.bUH[d], *bUL = P.bUL[d];
  const float *bias0 = P.bias[d], *bias1 = P.bias[d] + G3;
  int par = s & 1;
  const u16 *a0H = P.hH[par][d], *a0L = P.hL[par][d];

  #pragma unroll
  for (int i = 0; i < 8; i++) {
    int sl = tid + i * 256;
    int pl = sl >> 10;
    int rm = sl & 1023;
    int row = rm >> 5;
    const u16* src = (pl ? a0L : a0H) + (size_t)(m0 + row) * 256 + (rm & 31) * 8;
    *(us8*)&As[(sl ^ (row & 7)) * 8] = *(const us8*)src;
  }
  __syncthreads();

  f32x4 acc[3][2];
  #pragma unroll
  for (int a = 0; a < 3; a++)
    #pragma unroll
    for (int mf = 0; mf < 2; mf++) acc[a][mf] = (f32x4){0.f, 0.f, 0.f, 0.f};

  #pragma unroll
  for (int i = 0; i < 8; i++) {
    short8 ah[2], al[2];
    #pragma unroll
    for (int mf = 0; mf < 2; mf++) {
      int rp = mf * 16 + fr;
      int kb = i * 4 + kq;
      ah[mf] = *(const short8*)&As[((rp * 32 + kb) ^ (fr & 7)) * 8];
      al[mf] = *(const short8*)&As[((1024 + rp * 32 + kb) ^ (fr & 7)) * 8];
    }
    #pragma unroll
    for (int st = 0; st < 3; st++) {
      size_t ro = (size_t)(st * 256 + jn) * 256 + i * 32 + kq * 8;
      short8 bh = *(const short8*)(bUH + ro);
      short8 bl = *(const short8*)(bUL + ro);
      #pragma unroll
      for (int mf = 0; mf < 2; mf++) {
        acc[st][mf] = __builtin_amdgcn_mfma_f32_16x16x32_bf16(ah[mf], bh, acc[st][mf], 0, 0, 0);
        acc[st][mf] = __builtin_amdgcn_mfma_f32_16x16x32_bf16(ah[mf], bl, acc[st][mf], 0, 0, 0);
        acc[st][mf] = __builtin_amdgcn_mfma_f32_16x16x32_bf16(al[mf], bh, acc[st][mf], 0, 0, 0);
      }
    }
  }

  float b0z = bias0[jn] + bias1[jn];
  float b0r = bias0[256 + jn] + bias1[256 + jn];
  float bxc = bias0[512 + jn];
  float bhc = bias1[512 + jn];
  const float *gxT = P.gxT[d];
  int rbase = kq * 4;
  float* hoF = P.hF[par][d];
  float* hnF = P.hF[par ^ 1][d];
  u16* hnH = P.hH[par ^ 1][d];
  u16* hnL = P.hL[par ^ 1][d];
  int pos = d ? (S_ - 1 - s) : s;
  u16* ssHp = P.ssH + (size_t)pos * BHsz;
  u16* ssLp = P.ssL + (size_t)pos * BHsz;
  int ssmode = (s < S_ / 2) ? 1 : 2;
  #pragma unroll
  for (int mf = 0; mf < 2; mf++)
    #pragma unroll
    for (int rr = 0; rr < 4; rr++) {
      int b = m0 + mf * 16 + rbase + rr;
      size_t o = (size_t)b * H_ + jn;
      int id = P.ids[b * S_ + (d ? (S_ - 1 - s) : s)];
      const float* T = gxT + (size_t)id * G3;
      float z = sigm(acc[0][mf][rr] + T[jn] + b0z);
      float r = sigm(acc[1][mf][rr] + T[256 + jn] + b0r);
      float c = tanhf(T[512 + jn] + bxc + r * (acc[2][mf][rr] + bhc));
      float hn = z * hoF[o] + (1.f - z) * c;
      hnF[o] = hn;
      u16 hi = f2bf(hn);
      u16 lo = f2bf(hn - bf2f(hi));
      hnH[o] = hi; hnL[o] = lo;
      if (ssmode == 1) {
        ssHp[o] = hi; ssLp[o] = lo;
      } else {
        float v = bf2f(ssHp[o]) + bf2f(ssLp[o]) + hn;
        u16 vh = f2bf(v);
        ssHp[o] = vh; ssLp[o] = f2bf(v - bf2f(vh));
      }
    }
}

template<int COOP>
__global__ __launch_bounds__(256, 2)
void enc_all(EncP P, int s_single) {
  __shared__ __align__(16) u16 As[2 * 32 * 256];   // 32 KB
  if constexpr (COOP) {
    cg::grid_group grid = cg::this_grid();
    for (int s = 0; s < S_; s++) {
      enc_step_body(P, s, As);
      if (s < S_ - 1) grid.sync();
    }
  } else {
    enc_step_body(P, s_single, As);
  }
}

// ================= fused decoder (coop or per-step) =================
struct DecP {
  u16 *hAH, *hAL;              // hAll planes [T][B][H]
  const u16 *s0H, *s0L;        // ss pos0 planes (t=0 hold)
  float *hF[2];
  u16 *ctxH, *ctxL;
  const u16 *bUH, *bUL, *bCH, *bCL;
  const float *gxT;
  const float *bias;           // dec_b (bias1 = +G3)
  const u16 *sWH, *sWL;        // att_st planes [j][k]
  const float *stb;
  const u16 *projbf, *ssHall;
  const float *attv;
  const int *ids;
};

__device__ __forceinline__ void dec_g_body(const DecP& P, int t, u16* As) {
  int bid = blockIdx.x;
  int tid = threadIdx.x;
  int lane = tid & 63, wv = tid >> 6;
  int fr = lane & 15, kq = lane >> 4;
  int xg = bid & 7, yg = bid >> 3;
  int m0 = yg * 32;
  int jn = xg * 32 + (wv & 1) * 16 + fr;
  int rb0 = (wv >> 1) * 16;
  const size_t BHsz = (size_t)B_ * H_;
  int par = t & 1;
  const u16 *a0H = t ? P.hAH + (size_t)(t - 1) * BHsz : P.s0H;
  const u16 *a0L = t ? P.hAL + (size_t)(t - 1) * BHsz : P.s0L;

  f32x4 acc[4];
  #pragma unroll
  for (int a = 0; a < 4; a++) acc[a] = (f32x4){0.f, 0.f, 0.f, 0.f};

  // ---- half 0: h panel x U ----
  #pragma unroll
  for (int i = 0; i < 8; i++) {
    int sl = tid + i * 256;
    int pl = sl >> 10;
    int rm = sl & 1023;
    int row = rm >> 5;
    const u16* src = (pl ? a0L : a0H) + (size_t)(m0 + row) * 256 + (rm & 31) * 8;
    *(us8*)&As[(sl ^ (row & 7)) * 8] = *(const us8*)src;
  }
  __syncthreads();
  #pragma unroll
  for (int i = 0; i < 8; i++) {
    int rp = rb0 + fr;
    int kb = i * 4 + kq;
    short8 ah = *(const short8*)&As[((rp * 32 + kb) ^ (fr & 7)) * 8];
    short8 al = *(const short8*)&As[((1024 + rp * 32 + kb) ^ (fr & 7)) * 8];
    #pragma unroll
    for (int st = 0; st < 3; st++) {
      size_t ro = (size_t)(st * 256 + jn) * 256 + i * 32 + kq * 8;
      short8 bh = *(const short8*)(P.bUH + ro);
      short8 bl = *(const short8*)(P.bUL + ro);
      int ai = (st < 2) ? st : 2;
      acc[ai] = __builtin_amdgcn_mfma_f32_16x16x32_bf16(ah, bh, acc[ai], 0, 0, 0);
      acc[ai] = __builtin_amdgcn_mfma_f32_16x16x32_bf16(ah, bl, acc[ai], 0, 0, 0);
      acc[ai] = __builtin_amdgcn_mfma_f32_16x16x32_bf16(al, bh, acc[ai], 0, 0, 0);
    }
  }
  __syncthreads();
  // ---- half 1: ctx panel x Wc ----
  #pragma unroll
  for (int i = 0; i < 8; i++) {
    int sl = tid + i * 256;
    int pl = sl >> 10;
    int rm = sl & 1023;
    int row = rm >> 5;
    const u16* src = (pl ? P.ctxL : P.ctxH) + (size_t)(m0 + row) * 256 + (rm & 31) * 8;
    *(us8*)&As[(sl ^ (row & 7)) * 8] = *(const us8*)src;
  }
  __syncthreads();
  #pragma unroll
  for (int i = 0; i < 8; i++) {
    int rp = rb0 + fr;
    int kb = i * 4 + kq;
    short8 ah = *(const short8*)&As[((rp * 32 + kb) ^ (fr & 7)) * 8];
    short8 al = *(const short8*)&As[((1024 + rp * 32 + kb) ^ (fr & 7)) * 8];
    #pragma unroll
    for (int st = 0; st < 3; st++) {
      size_t ro = (size_t)(st * 256 + jn) * 256 + i * 32 + kq * 8;
      short8 bh = *(const short8*)(P.bCH + ro);
      short8 bl = *(const short8*)(P.bCL + ro);
      int ai = (st < 2) ? st : 3;
      acc[ai] = __builtin_amdgcn_mfma_f32_16x16x32_bf16(ah, bh, acc[ai], 0, 0, 0);
      acc[ai] = __builtin_amdgcn_mfma_f32_16x16x32_bf16(ah, bl, acc[ai], 0, 0, 0);
      acc[ai] = __builtin_amdgcn_mfma_f32_16x16x32_bf16(al, bh, acc[ai], 0, 0, 0);
    }
  }

  // ---- gate epilogue ----
  float b0z = P.bias[jn] + P.bias[G3 + jn];
  float b0r = P.bias[256 + jn] + P.bias[G3 + 256 + jn];
  float bxc = P.bias[512 + jn];
  float bhc = P.bias[G3 + 512 + jn];
  int rbase = kq * 4;
  float* hoF = P.hF[par];
  float* hnF = P.hF[par ^ 1];
  u16* hnH = P.hAH + (size_t)t * BHsz;
  u16* hnL = P.hAL + (size_t)t * BHsz;
  #pragma unroll
  for (int rr = 0; rr < 4; rr++) {
    int b = m0 + rb0 + rbase + rr;
    size_t o = (size_t)b * H_ + jn;
    int id = (t == 0) ? BOW_ : P.ids[b * T_ + t - 1];
    const float* T = P.gxT + (size_t)id * G3;
    float z = sigm(acc[0][rr] + T[jn] + b0z);
    float r = sigm(acc[1][rr] + T[256 + jn] + b0r);
    float c = tanhf(T[512 + jn] + bxc + acc[3][rr] + r * (acc[2][rr] + bhc));
    float hprev = t ? hoF[o] : (bf2f(P.s0H[o]) + bf2f(P.s0L[o]));
    float hn = z * hprev + (1.f - z) * c;
    hnF[o] = hn;
    u16 hi = f2bf(hn);
    hnH[o] = hi; hnL[o] = f2bf(hn - bf2f(hi));
  }
}

__device__ __forceinline__ void dec_la_body(const DecP& P, int t, u16* As) {
  int bid = blockIdx.x;
  if (bid >= 128) return;
  int tid = threadIdx.x;
  int lane = tid & 63, wv = tid >> 6;
  int fr = lane & 15, kq = lane >> 4;
  const size_t BHsz = (size_t)B_ * H_;
  u16* hstage = As;                         // 16 KB (aliased by e_lds later)
  float* p_lds = (float*)(As + 8192);       // 16 KB
  float* e_lds = (float*)As;                // reuse after LP
  int r0 = bid * 16;
  float vq[4];
  #pragma unroll
  for (int q = 0; q < 4; q++) vq[q] = P.attv[q * 64 + lane];

  const u16* hH_ = P.hAH + (size_t)t * BHsz;
  const u16* hL_ = P.hAL + (size_t)t * BHsz;
  #pragma unroll
  for (int i = 0; i < 4; i++) {
    int sl = tid + i * 256;
    int pl = sl >> 9;
    int rm = sl & 511;
    int row = rm >> 5;
    int k = (rm & 31) * 8;
    const u16* src = (pl ? hL_ : hH_) + (size_t)(r0 + row) * 256 + k;
    *(us8*)&hstage[(sl ^ (row & 7)) * 8] = *(const us8*)src;
  }
  __syncthreads();
  // LP: wave wv covers j = wv*64 .. +64 for all 16 rows
  f32x4 pacc[4];
  #pragma unroll
  for (int n = 0; n < 4; n++) pacc[n] = (f32x4){0.f, 0.f, 0.f, 0.f};
  #pragma unroll
  for (int c = 0; c < 8; c++) {
    int kb = c * 4 + kq;
    short8 ah = *(const short8*)&hstage[((fr * 32 + kb) ^ (fr & 7)) * 8];
    short8 al = *(const short8*)&hstage[((512 + fr * 32 + kb) ^ (fr & 7)) * 8];
    #pragma unroll
    for (int n = 0; n < 4; n++) {
      int j = wv * 64 + n * 16 + fr;
      size_t ro = (size_t)j * 256 + c * 32 + kq * 8;
      short8 bh = *(const short8*)(P.sWH + ro);
      short8 bl = *(const short8*)(P.sWL + ro);
      pacc[n] = __builtin_amdgcn_mfma_f32_16x16x32_bf16(ah, bh, pacc[n], 0, 0, 0);
      pacc[n] = __builtin_amdgcn_mfma_f32_16x16x32_bf16(ah, bl, pacc[n], 0, 0, 0);
      pacc[n] = __builtin_amdgcn_mfma_f32_16x16x32_bf16(al, bh, pacc[n], 0, 0, 0);
    }
  }
  __syncthreads();   // all LP reads of hstage done before e_lds overwrites it
  #pragma unroll
  for (int n = 0; n < 4; n++) {
    int j = wv * 64 + n * 16 + fr;
    float bj = P.stb[j];
    #pragma unroll
    for (int rr = 0; rr < 4; rr++)
      p_lds[(kq * 4 + rr) * 256 + j] = pacc[n][rr] + bj;
  }
  __syncthreads();
  // scores: wave wv handles local rows wv*4 .. wv*4+3
  #pragma unroll
  for (int u = 0; u < 4; u++) {
    int lr = wv * 4 + u;
    int b = r0 + lr;
    float pq[4];
    #pragma unroll
    for (int q = 0; q < 4; q++) pq[q] = p_lds[lr * 256 + q * 64 + lane];
    #pragma unroll 8
    for (int s2 = 0; s2 < S_; s2++) {
      const u16* pr = P.projbf + ((size_t)s2 * B_ + b) * H_;
      float part = 0.f;
      #pragma unroll
      for (int q = 0; q < 4; q++)
        part += tanhf(bf2f(pr[q * 64 + lane]) + pq[q]) * vq[q];
      #pragma unroll
      for (int off = 32; off; off >>= 1) part += __shfl_xor(part, off);
      if (lane == 0) e_lds[lr * 32 + s2] = part;
    }
  }
  __syncthreads();
  #pragma unroll
  for (int u = 0; u < 4; u++) {
    int lr = wv * 4 + u;
    int b = r0 + lr;
    float m = -1e30f;
    #pragma unroll
    for (int s2 = 0; s2 < S_; s2++) m = fmaxf(m, e_lds[lr * 32 + s2]);
    float wsr[S_]; float den = 0.f;
    #pragma unroll
    for (int s2 = 0; s2 < S_; s2++) { wsr[s2] = expf(e_lds[lr * 32 + s2] - m); den += wsr[s2]; }
    float inv = 1.f / den;
    float cacc[4] = {0.f, 0.f, 0.f, 0.f};
    #pragma unroll 8
    for (int s2 = 0; s2 < S_; s2++) {
      float w = wsr[s2] * inv;
      #pragma unroll
      for (int q = 0; q < 4; q++)
        cacc[q] = fmaf(w, bf2f(P.ssHall[((size_t)s2 * B_ + b) * H_ + q * 64 + lane]), cacc[q]);
    }
    #pragma unroll
    for (int q = 0; q < 4; q++) {
      float v = cacc[q];
      u16 hi = f2bf(v);
      size_t o = (size_t)b * H_ + q * 64 + lane;
      P.ctxH[o] = hi; P.ctxL[o] = f2bf(v - bf2f(hi));
    }
  }
}

template<int COOP>
__global__ __launch_bounds__(256, 2)
void dec_all(DecP P, int t_single, int phase) {
  __shared__ __align__(16) u16 As[2 * 32 * 256];   // 32 KB
  if constexpr (COOP) {
    cg::grid_group grid = cg::this_grid();
    for (int t = 0; t < T_; t++) {
      dec_g_body(P, t, As);
      if (t == T_ - 1) break;
      grid.sync();
      dec_la_body(P, t, As);
      grid.sync();
    }
  } else {
    if (phase == 0) dec_g_body(P, t_single, As);
    else            dec_la_body(P, t_single, As);
  }
}

// ---------------- host ----------------
extern "C" void kernel_launch(void* const* d_in, const int* in_sizes, int n_in,
                              void* d_out, int out_size, void* d_ws, size_t ws_size,
                              hipStream_t stream) {
  const float* src_emb   = (const float*)d_in[0];
  const float* tgt_emb   = (const float*)d_in[1];
  const float* enc_f_W   = (const float*)d_in[2];
  const float* enc_f_U   = (const float*)d_in[3];
  const float* enc_f_b   = (const float*)d_in[4];
  const float* enc_b_W   = (const float*)d_in[5];
  const float* enc_b_U   = (const float*)d_in[6];
  const float* enc_b_b   = (const float*)d_in[7];
  const float* dec_W     = (const float*)d_in[8];
  const float* dec_U     = (const float*)d_in[9];
  const float* dec_b     = (const float*)d_in[10];
  const float* out_W     = (const float*)d_in[11];
  const float* out_b     = (const float*)d_in[12];
  const float* att_src_W = (const float*)d_in[13];
  const float* att_src_b = (const float*)d_in[14];
  const float* att_st_W  = (const float*)d_in[15];
  const float* att_st_b  = (const float*)d_in[16];
  const float* att_v     = (const float*)d_in[17];
  const int* source_ids  = (const int*)d_in[19];
  const int* target_ids  = (const int*)d_in[20];
  float* out = (float*)d_out;

  char* base = (char*)d_ws;
  size_t off = 0;
  auto allocB = [&](size_t bytes) { void* p = base + off; off = (off + bytes + 255) & ~255UL; return p; };
  const size_t BH = (size_t)B_ * H_;

  u16* ssH    = (u16*)allocB((size_t)S_ * BH * 2);
  u16* ssL    = (u16*)allocB((size_t)S_ * BH * 2);
  u16* projbf = (u16*)allocB((size_t)S_ * BH * 2);
  float* pbuf = (float*)allocB(BH * 4);
  u16* ctxh = (u16*)allocB(BH * 2);
  u16* ctxl = (u16*)allocB(BH * 2);

  float* encF0 = (float*)allocB(2 * BH * 4);
  u16*  encPl0 = (u16*)allocB(4 * BH * 2);
  float* encF1 = (float*)allocB(2 * BH * 4);
  u16*  encPl1 = (u16*)allocB(4 * BH * 2);
  float* encF[2][2]  = { { encF0, encF0 + BH }, { encF1, encF1 + BH } };
  u16*  encH[2][2]   = { { encPl0, encPl0 + 2 * BH }, { encPl1, encPl1 + 2 * BH } };
  u16*  encL[2][2]   = { { encPl0 + BH, encPl0 + 3 * BH }, { encPl1 + BH, encPl1 + 3 * BH } };

  float* hDecF[2] = { (float*)allocB(BH * 4), (float*)allocB(BH * 4) };
  u16* hAllH = (u16*)allocB((size_t)T_ * BH * 2);
  u16* hAllL = (u16*)allocB((size_t)T_ * BH * 2);

  auto planes2 = [&](size_t n, u16*& h, u16*& l) { h = (u16*)allocB(n * 2); l = (u16*)allocB(n * 2); };
  u16 *UtFh,*UtFl,*UtBh,*UtBl,*WtFh,*WtFl,*WtBh,*WtBl;
  u16 *dUth,*dUtl,*dWcth,*dWctl,*dWxth,*dWxtl;
  u16 *oWth,*oWtl,*aStth,*aSttl,*aSrth,*aSrtl;
  u16 *sEh,*sEl,*tEh,*tEl;
  planes2((size_t)G3*H_, UtFh, UtFl);   planes2((size_t)G3*H_, UtBh, UtBl);
  planes2((size_t)G3*D_, WtFh, WtFl);   planes2((size_t)G3*D_, WtBh, WtBl);
  planes2((size_t)G3*H_, dUth, dUtl);   planes2((size_t)G3*H_, dWcth, dWctl);
  planes2((size_t)G3*D_, dWxth, dWxtl);
  planes2((size_t)H_*VT_, oWth, oWtl);
  planes2((size_t)H_*H_, aSrth, aSrtl);
  planes2((size_t)H_*H_, aStth, aSttl);
  planes2((size_t)VT_*D_, sEh, sEl);    planes2((size_t)VT_*D_, tEh, tEl);
  float* Tf = (float*)allocB((size_t)VT_ * G3 * 4);
  float* Tb = (float*)allocB((size_t)VT_ * G3 * 4);
  float* Td = (float*)allocB((size_t)VT_ * G3 * 4);

  TPack P;
  P.m[0] = { enc_f_U,          UtFh, UtFl, 256, 768, 0   };
  P.m[1] = { enc_b_U,          UtBh, UtBl, 256, 768, 48  };
  P.m[2] = { dec_U,            dUth, dUtl, 256, 768, 96  };
  P.m[3] = { dec_W + 128 * G3, dWcth, dWctl, 256, 768, 144 };
  P.m[4] = { enc_f_W,          WtFh, WtFl, 128, 768, 192 };
  P.m[5] = { enc_b_W,          WtBh, WtBl, 128, 768, 216 };
  P.m[6] = { dec_W,            dWxth, dWxtl, 128, 768, 240 };
  P.m[7] = { out_W,            oWth, oWtl, 256, 256, 264 };
  P.m[8] = { att_src_W,        aSrth, aSrtl, 256, 256, 280 };
  P.m[9] = { att_st_W,         aStth, aSttl, 256, 256, 296 };
  wsplit_t<<<312, 256, 0, stream>>>(P);
  esplit<<<(2 * VT_ * D_ + 255) / 256, 256, 0, stream>>>(src_emb, tgt_emb, sEh, sEl, tEh, tEl, VT_ * D_);

  // gx tables
  {
    PLeg tf = { sEh, sEl, D_, WtFh, WtFl, D_, nullptr, Tf, G3, 0, VT_, G3, D_ };
    PLeg tb = { sEh, sEl, D_, WtBh, WtBl, D_, nullptr, Tb, G3, 0, VT_, G3, D_ };
    gemm_pl<<<dim3(6, 2, 2), 256, 0, stream>>>(tf, tb);
    PLeg td = { tEh, tEl, D_, dWxth, dWxtl, D_, nullptr, Td, G3, 0, VT_, G3, D_ };
    gemm_pl<<<dim3(6, 2, 1), 256, 0, stream>>>(td, td);
  }

  hipMemsetAsync(encF0, 0, 2 * BH * 4, stream);
  hipMemsetAsync(encPl0, 0, 4 * BH * 2, stream);

  // ---- cooperative capability precheck ----
  int devId = 0;
  hipGetDevice(&devId);
  int coopAttr = 0;
  hipDeviceGetAttribute(&coopAttr, hipDeviceAttributeCooperativeLaunch, devId);
  int numCU = 0;
  hipDeviceGetAttribute(&numCU, hipDeviceAttributeMultiprocessorCount, devId);
  int nbE = 0, nbD = 0;
  hipOccupancyMaxActiveBlocksPerMultiprocessor(&nbE, (const void*)enc_all<1>, 256, 0);
  hipOccupancyMaxActiveBlocksPerMultiprocessor(&nbD, (const void*)dec_all<1>, 256, 0);
  bool coopE = coopAttr && ((long)nbE * numCU >= 512);
  bool coopD = coopAttr && ((long)nbD * numCU >= 512);

  // ---- encoder ----
  EncP Pe;
  for (int par = 0; par < 2; par++)
    for (int d = 0; d < 2; d++) {
      Pe.hH[par][d] = encH[par][d];
      Pe.hL[par][d] = encL[par][d];
      Pe.hF[par][d] = encF[par][d];
    }
  Pe.bUH[0] = UtFh; Pe.bUL[0] = UtFl;
  Pe.bUH[1] = UtBh; Pe.bUL[1] = UtBl;
  Pe.gxT[0] = Tf;   Pe.gxT[1] = Tb;
  Pe.bias[0] = enc_f_b; Pe.bias[1] = enc_b_b;
  Pe.ssH = ssH; Pe.ssL = ssL;
  Pe.ids = source_ids;
  if (coopE) {
    int zero = 0;
    void* eargs[] = { &Pe, &zero };
    hipError_t e = hipLaunchCooperativeKernel((void*)enc_all<1>, dim3(512), dim3(256), eargs, 0, stream);
    if (e != hipSuccess) { (void)hipGetLastError(); coopE = false; }
  }
  if (!coopE) {
    for (int s = 0; s < S_; s++)
      enc_all<0><<<dim3(512), 256, 0, stream>>>(Pe, s);
  }

  // ---- proj (bf16) + p0 (f32), then initial attention ----
  {
    PLeg proj = { ssH, ssL, H_, aSrth, aSrtl, H_, att_src_b, projbf, H_, 1, S_ * B_, H_, H_ };
    PLeg p0   = { ssH, ssL, H_, aStth, aSttl, H_, att_st_b,  pbuf,   H_, 0, B_,      H_, H_ };
    gemm_pl<<<dim3(2, 512, 2), 256, 0, stream>>>(proj, p0);
  }
  attend_k<<<B_, 256, 0, stream>>>(projbf, ssH, pbuf, att_v, ctxh, ctxl);

  // ---- decoder ----
  DecP Pd;
  Pd.hAH = hAllH; Pd.hAL = hAllL;
  Pd.s0H = ssH;   Pd.s0L = ssL;
  Pd.hF[0] = hDecF[0]; Pd.hF[1] = hDecF[1];
  Pd.ctxH = ctxh; Pd.ctxL = ctxl;
  Pd.bUH = dUth; Pd.bUL = dUtl; Pd.bCH = dWcth; Pd.bCL = dWctl;
  Pd.gxT = Td;
  Pd.bias = dec_b;
  Pd.sWH = aStth; Pd.sWL = aSttl;
  Pd.stb = att_st_b;
  Pd.projbf = projbf; Pd.ssHall = ssH;
  Pd.attv = att_v;
  Pd.ids = target_ids;
  if (coopD) {
    int zero = 0, zero2 = 0;
    void* dargs[] = { &Pd, &zero, &zero2 };
    hipError_t e = hipLaunchCooperativeKernel((void*)dec_all<1>, dim3(512), dim3(256), dargs, 0, stream);
    if (e != hipSuccess) { (void)hipGetLastError(); coopD = false; }
  }
  if (!coopD) {
    for (int t = 0; t < T_; t++) {
      dec_all<0><<<dim3(512), 256, 0, stream>>>(Pd, t, 0);
      if (t < T_ - 1)
        dec_all<0><<<dim3(128), 256, 0, stream>>>(Pd, t, 1);
    }
  }

  // ---- batched logits ----
  {
    PLeg LO = { hAllH, hAllL, H_, oWth, oWtl, H_, out_b, out, 0, 2, T_ * B_, VT_, H_ };
    gemm_pl<<<dim3(2, 512, 1), 256, 0, stream>>>(LO, LO);
  }
}